// Round 5
// baseline (838.991 us; speedup 1.0000x reference)
//
#include <hip/hip_runtime.h>

#define B_TOT 65536
#define T_STEPS 10
#define D_IN 16
#define H 64
#define G4H 256
#define D_MLP 30
#define D_OUT 4
#define PSTR 66          // h-plane row stride (shorts); odd dword count -> <=4-way conflicts

typedef short short8 __attribute__((ext_vector_type(8)));
typedef float float4_t __attribute__((ext_vector_type(4)));
typedef __bf16 bf16x8_t __attribute__((ext_vector_type(8)));

static __device__ __forceinline__ short f2bf(float f) {  // round-half-up (activations)
    unsigned u = __builtin_bit_cast(unsigned, f);
    return (short)(unsigned short)((u + 0x8000u) >> 16);
}
static __device__ __forceinline__ short f2bf_rne(float f) {  // weights
    unsigned u = __builtin_bit_cast(unsigned, f);
    unsigned r = (u + 0x7FFFu + ((u >> 16) & 1u)) >> 16;
    return (short)(unsigned short)r;
}
static __device__ __forceinline__ float bf2f(short s) {
    unsigned u = ((unsigned)(unsigned short)s) << 16;
    return __builtin_bit_cast(float, u);
}
static __device__ __forceinline__ float4_t mfma16(short8 a, short8 b, float4_t c) {
    return __builtin_amdgcn_mfma_f32_16x16x32_bf16(
        __builtin_bit_cast(bf16x8_t, a), __builtin_bit_cast(bf16x8_t, b), c, 0, 0, 0);
}
static __device__ __forceinline__ float sigm(float x) {
    return __builtin_amdgcn_rcpf(1.0f + __expf(-x));
}
static __device__ __forceinline__ float tanh_f(float x) {
    return 1.0f - 2.0f * __builtin_amdgcn_rcpf(1.0f + __expf(2.0f * x));
}

// ---- workspace layout (bytes) ----
// wu1_sw @0       : 48 frags x 64 lanes x 8 shorts = 49152   (A1=[h1(0:64)|x(64:80)|pad])
// wu2_sw @49152   : 48 frags = 49152                          (A2=[d(0:32)|h2(32:96)])
// wd_sw  @98304   : 4 frags  = 4096                           (d = h1 @ Wd, cols padded 30->32)
// bz1    @102400  : 256 f32
// b2p    @103424  : 256 f32
// bdp    @104448  : 32 f32
// dg     @104576  : [T][B][32] bf16 = 41943040
#define WS_WU1 0
#define WS_WU2 49152
#define WS_WD  98304
#define WS_BZ1 102400
#define WS_B2P 103424
#define WS_BDP 104448
#define WS_DG  104576

// Pre-swizzle weights into MFMA B-fragment order: frag f, lane l, elem e ->
// B[k = kt*32 + (l>>4)*8 + e][n]. Stored as [f][lane][8] so frag read = 1 ds_read_b128.
__global__ void precompute(const float* __restrict__ W1, const float* __restrict__ U1,
                           const float* __restrict__ b1, const float* __restrict__ Wd,
                           const float* __restrict__ bd, const float* __restrict__ W2,
                           const float* __restrict__ U2, const float* __restrict__ b2,
                           short* __restrict__ wu1_sw, short* __restrict__ wu2_sw,
                           short* __restrict__ wd_sw, float* __restrict__ bz1,
                           float* __restrict__ b2p, float* __restrict__ bdp) {
    const int lane = threadIdx.x;  // 64
    const int b = blockIdx.x;      // 101
    if (b < 48) {
        const int f = b, jt = f / 12, g = (f / 3) & 3, kt = f % 3;
        const int col = g * 64 + jt * 16 + (lane & 15);
        for (int e = 0; e < 8; ++e) {
            const int k = kt * 32 + (lane >> 4) * 8 + e;
            float v = 0.0f;
            if (k < 64)      v = U1[k * G4H + col];          // h1 rows
            else if (k < 80) v = W1[(k - 64) * G4H + col];   // x rows
            wu1_sw[(f * 64 + lane) * 8 + e] = f2bf_rne(v);
        }
    } else if (b < 96) {
        const int f = b - 48, jt = f / 12, g = (f / 3) & 3, kt = f % 3;
        const int col = g * 64 + jt * 16 + (lane & 15);
        for (int e = 0; e < 8; ++e) {
            const int k = kt * 32 + (lane >> 4) * 8 + e;
            float v = 0.0f;
            if (k < 32)      v = (k < D_MLP) ? W2[k * G4H + col] : 0.0f;  // d rows
            else             v = U2[(k - 32) * G4H + col];                 // h2 rows
            wu2_sw[(f * 64 + lane) * 8 + e] = f2bf_rne(v);
        }
    } else if (b < 100) {
        const int fd = b - 96, nt = fd >> 1, kt = fd & 1;
        const int col = nt * 16 + (lane & 15);
        for (int e = 0; e < 8; ++e) {
            const int k = kt * 32 + (lane >> 4) * 8 + e;  // h1 row 0..63
            const float v = (col < D_MLP) ? Wd[k * D_MLP + col] : 0.0f;
            wd_sw[(fd * 64 + lane) * 8 + e] = f2bf_rne(v);
        }
    } else {
        for (int i = 0; i < 4; ++i) {
            const int c = i * 64 + lane;
            bz1[c] = b1[c];
            b2p[c] = b2[c];
        }
        if (lane < 32) bdp[lane] = (lane < D_MLP) ? bd[lane] : 0.0f;
    }
}

// ---------------- lstm1: autonomous waves, d = h1@Wd+bd out to global ----------------
__global__ __launch_bounds__(256)
__attribute__((amdgpu_waves_per_eu(3, 4)))
void lstm1(const float* __restrict__ x, const short* __restrict__ wu1_sw,
           const short* __restrict__ wd_sw, const float* __restrict__ bz1,
           const float* __restrict__ bdp, short* __restrict__ dg) {
    __shared__ __align__(16) short W[40 * 512];        // frags 0..35 gate (jt 0..2) + 4 wd
    __shared__ __align__(16) short plane[4][16 * PSTR];

    const int tid = threadIdx.x, lane = tid & 63, wave = tid >> 6;
    const int q = lane >> 4, n = lane & 15;
    const int rowbase = blockIdx.x * 64 + wave * 16;

    // stage LDS weights (one barrier, then none)
    for (int i = tid; i < 40 * 64; i += 256) {
        const short8 v = (i < 36 * 64) ? ((const short8*)wu1_sw)[i]
                                       : ((const short8*)wd_sw)[i - 36 * 64];
        ((short8*)W)[i] = v;
    }
    // jt=3 gate frags live in registers
    short8 wf[4][3];
#pragma unroll
    for (int g = 0; g < 4; ++g)
#pragma unroll
        for (int kt = 0; kt < 3; ++kt)
            wf[g][kt] = ((const short8*)wu1_sw)[(36 + g * 3 + kt) * 64 + lane];
    float bz[4][4];
#pragma unroll
    for (int jt = 0; jt < 4; ++jt)
#pragma unroll
        for (int g = 0; g < 4; ++g) bz[jt][g] = bz1[g * 64 + jt * 16 + n];
    const float bdv0 = bdp[n], bdv1 = bdp[16 + n];

    short* pl = &plane[wave][0];
    for (int i = lane; i < 16 * PSTR; i += 64) pl[i] = 0;

    float4_t c1[4];
#pragma unroll
    for (int jt = 0; jt < 4; ++jt) c1[jt] = (float4_t){0, 0, 0, 0};

    __syncthreads();  // weights visible; no further barriers

    const float* xlane = x + (size_t)(rowbase + n) * (T_STEPS * D_IN) + (q & 1) * 8;
    short* dlane = dg + (size_t)(rowbase + q * 4) * 32 + n;

    for (int t = 0; t < T_STEPS; ++t) {
        // A-frags: h1_{t-1} from private plane (k-tiles 0,1)
        const short8 ah0 = *(const short8*)&pl[n * PSTR + q * 8];
        const short8 ah1 = *(const short8*)&pl[n * PSTR + 32 + q * 8];

        // pipelined d_{t-1} = h1_{t-1} @ Wd + bd  (uses same A-frags)
        if (t > 0) {
            const short8* WD = (const short8*)&W[36 * 512];
            float4_t d0 = (float4_t){bdv0, bdv0, bdv0, bdv0};
            float4_t d1 = (float4_t){bdv1, bdv1, bdv1, bdv1};
            d0 = mfma16(ah0, WD[0 * 64 + lane], d0);
            d0 = mfma16(ah1, WD[1 * 64 + lane], d0);
            d1 = mfma16(ah0, WD[2 * 64 + lane], d1);
            d1 = mfma16(ah1, WD[3 * 64 + lane], d1);
            short* db = dlane + (size_t)(t - 1) * (B_TOT * 32);
#pragma unroll
            for (int jj = 0; jj < 4; ++jj) {
                db[jj * 32] = f2bf(d0[jj]);
                db[jj * 32 + 16] = f2bf(d1[jj]);
            }
        }

        // x_t A-frag (k-tile 2): lanes q<2 hold x cols, q>=2 hold zero-weight rows
        short8 a2 = (short8){0, 0, 0, 0, 0, 0, 0, 0};
        if (q < 2) {
            const float* xp = xlane + t * D_IN;
            const float4 x0 = *(const float4*)xp;
            const float4 x1 = *(const float4*)(xp + 4);
            a2[0] = f2bf(x0.x); a2[1] = f2bf(x0.y); a2[2] = f2bf(x0.z); a2[3] = f2bf(x0.w);
            a2[4] = f2bf(x1.x); a2[5] = f2bf(x1.y); a2[6] = f2bf(x1.z); a2[7] = f2bf(x1.w);
        }

#pragma unroll
        for (int jt = 0; jt < 4; ++jt) {
            float4_t ac[4];
#pragma unroll
            for (int g = 0; g < 4; ++g) {
                short8 b0, b1, b2v;
                if (jt < 3) {
                    const int fb = (jt * 4 + g) * 3;
                    b0 = ((const short8*)W)[(fb + 0) * 64 + lane];
                    b1 = ((const short8*)W)[(fb + 1) * 64 + lane];
                    b2v = ((const short8*)W)[(fb + 2) * 64 + lane];
                } else { b0 = wf[g][0]; b1 = wf[g][1]; b2v = wf[g][2]; }
                float4_t c = (float4_t){bz[jt][g], bz[jt][g], bz[jt][g], bz[jt][g]};
                c = mfma16(ah0, b0, c);
                c = mfma16(ah1, b1, c);
                c = mfma16(a2, b2v, c);
                ac[g] = c;
            }
#pragma unroll
            for (int jj = 0; jj < 4; ++jj) {
                const float iv = sigm(ac[0][jj]);
                const float fv = sigm(ac[1][jj]);
                const float gv = tanh_f(ac[2][jj]);
                const float ov = sigm(ac[3][jj]);
                const float cn = fv * c1[jt][jj] + iv * gv;
                c1[jt][jj] = cn;
                pl[(q * 4 + jj) * PSTR + jt * 16 + n] = f2bf(ov * tanh_f(cn));
            }
        }
    }
    // final d_9
    {
        const short8 ah0 = *(const short8*)&pl[n * PSTR + q * 8];
        const short8 ah1 = *(const short8*)&pl[n * PSTR + 32 + q * 8];
        const short8* WD = (const short8*)&W[36 * 512];
        float4_t d0 = (float4_t){bdv0, bdv0, bdv0, bdv0};
        float4_t d1 = (float4_t){bdv1, bdv1, bdv1, bdv1};
        d0 = mfma16(ah0, WD[0 * 64 + lane], d0);
        d0 = mfma16(ah1, WD[1 * 64 + lane], d0);
        d1 = mfma16(ah0, WD[2 * 64 + lane], d1);
        d1 = mfma16(ah1, WD[3 * 64 + lane], d1);
        short* db = dlane + (size_t)(T_STEPS - 1) * (B_TOT * 32);
#pragma unroll
        for (int jj = 0; jj < 4; ++jj) {
            db[jj * 32] = f2bf(d0[jj]);
            db[jj * 32 + 16] = f2bf(d1[jj]);
        }
    }
}

// ---------------- lstm2: autonomous waves, d from global as A-frags, fused projection ----------------
__global__ __launch_bounds__(256)
__attribute__((amdgpu_waves_per_eu(3, 4)))
void lstm2(const short* __restrict__ dg, const short* __restrict__ wu2_sw,
           const float* __restrict__ b2p, const float* __restrict__ Wf,
           const float* __restrict__ bfin, float* __restrict__ out) {
    __shared__ __align__(16) short W[36 * 512];
    __shared__ __align__(16) short plane[4][16 * PSTR];

    const int tid = threadIdx.x, lane = tid & 63, wave = tid >> 6;
    const int q = lane >> 4, n = lane & 15;
    const int rowbase = blockIdx.x * 64 + wave * 16;

    for (int i = tid; i < 36 * 64; i += 256)
        ((short8*)W)[i] = ((const short8*)wu2_sw)[i];
    short8 wf[4][3];
#pragma unroll
    for (int g = 0; g < 4; ++g)
#pragma unroll
        for (int kt = 0; kt < 3; ++kt)
            wf[g][kt] = ((const short8*)wu2_sw)[(36 + g * 3 + kt) * 64 + lane];
    float bz[4][4];
#pragma unroll
    for (int jt = 0; jt < 4; ++jt)
#pragma unroll
        for (int g = 0; g < 4; ++g) bz[jt][g] = b2p[g * 64 + jt * 16 + n];

    short* pl = &plane[wave][0];
    for (int i = lane; i < 16 * PSTR; i += 64) pl[i] = 0;

    float4_t c2[4];
#pragma unroll
    for (int jt = 0; jt < 4; ++jt) c2[jt] = (float4_t){0, 0, 0, 0};

    __syncthreads();  // weights visible; no further barriers

    const short8* dfr = (const short8*)dg + (size_t)(rowbase + n) * 4 + q;

    for (int t = 0; t < T_STEPS; ++t) {
        const short8 ad = dfr[(size_t)t * (B_TOT * 4)];          // d_t (k-tile 0)
        const short8 ah0 = *(const short8*)&pl[n * PSTR + q * 8];       // h2 k-tile 1
        const short8 ah1 = *(const short8*)&pl[n * PSTR + 32 + q * 8];  // h2 k-tile 2

#pragma unroll
        for (int jt = 0; jt < 4; ++jt) {
            float4_t ac[4];
#pragma unroll
            for (int g = 0; g < 4; ++g) {
                short8 b0, b1, b2v;
                if (jt < 3) {
                    const int fb = (jt * 4 + g) * 3;
                    b0 = ((const short8*)W)[(fb + 0) * 64 + lane];
                    b1 = ((const short8*)W)[(fb + 1) * 64 + lane];
                    b2v = ((const short8*)W)[(fb + 2) * 64 + lane];
                } else { b0 = wf[g][0]; b1 = wf[g][1]; b2v = wf[g][2]; }
                float4_t c = (float4_t){bz[jt][g], bz[jt][g], bz[jt][g], bz[jt][g]};
                c = mfma16(ad, b0, c);
                c = mfma16(ah0, b1, c);
                c = mfma16(ah1, b2v, c);
                ac[g] = c;
            }
#pragma unroll
            for (int jj = 0; jj < 4; ++jj) {
                const float iv = sigm(ac[0][jj]);
                const float fv = sigm(ac[1][jj]);
                const float gv = fmaxf(ac[2][jj], 0.0f);
                const float ov = sigm(ac[3][jj]);
                const float cn = fv * c2[jt][jj] + iv * gv;
                c2[jt][jj] = cn;
                pl[(q * 4 + jj) * PSTR + jt * 16 + n] = f2bf(ov * fmaxf(cn, 0.0f));
            }
        }
    }

    // out = h2_9 @ Wf + bf  (per-wave, from private plane)
    {
        const int r = lane >> 2, cc = lane & 3;
        float s = bfin[cc];
#pragma unroll
        for (int kb = 0; kb < 8; ++kb) {
            const short8 h8 = *(const short8*)&pl[r * PSTR + kb * 8];
#pragma unroll
            for (int e = 0; e < 8; ++e)
                s += bf2f(h8[e]) * Wf[(kb * 8 + e) * D_OUT + cc];
        }
        out[(size_t)(rowbase + r) * D_OUT + cc] = s;
    }
}

extern "C" void kernel_launch(void* const* d_in, const int* in_sizes, int n_in,
                              void* d_out, int out_size, void* d_ws, size_t ws_size,
                              hipStream_t stream) {
    const float* x  = (const float*)d_in[0];
    const float* W1 = (const float*)d_in[1];
    const float* U1 = (const float*)d_in[2];
    const float* b1 = (const float*)d_in[3];
    const float* Wd = (const float*)d_in[4];
    const float* bd = (const float*)d_in[5];
    const float* W2 = (const float*)d_in[6];
    const float* U2 = (const float*)d_in[7];
    const float* b2 = (const float*)d_in[8];
    const float* Wf = (const float*)d_in[9];
    const float* bf = (const float*)d_in[10];
    float* out = (float*)d_out;

    char* ws = (char*)d_ws;
    short* wu1_sw = (short*)(ws + WS_WU1);
    short* wu2_sw = (short*)(ws + WS_WU2);
    short* wd_sw  = (short*)(ws + WS_WD);
    float* bz1    = (float*)(ws + WS_BZ1);
    float* b2p    = (float*)(ws + WS_B2P);
    float* bdp    = (float*)(ws + WS_BDP);
    short* dg     = (short*)(ws + WS_DG);

    precompute<<<101, 64, 0, stream>>>(W1, U1, b1, Wd, bd, W2, U2, b2,
                                       wu1_sw, wu2_sw, wd_sw, bz1, b2p, bdp);
    lstm1<<<B_TOT / 64, 256, 0, stream>>>(x, wu1_sw, wd_sw, bz1, bdp, dg);
    lstm2<<<B_TOT / 64, 256, 0, stream>>>(dg, wu2_sw, b2p, Wf, bf, out);
}

// Round 6
// 539.829 us; speedup vs baseline: 1.5542x; 1.5542x over previous
//
#include <hip/hip_runtime.h>

#define B_TOT 65536
#define T_STEPS 10
#define D_IN 16
#define H 64
#define G4H 256
#define D_MLP 30
#define D_OUT 4
#define PSTR 66          // h-plane row stride (shorts)
#define DSTR 34          // d staging tile row stride (shorts): 32 cols + pad

typedef short short8 __attribute__((ext_vector_type(8)));
typedef float float4_t __attribute__((ext_vector_type(4)));
typedef __bf16 bf16x8_t __attribute__((ext_vector_type(8)));

static __device__ __forceinline__ short f2bf(float f) {  // round-half-up (activations)
    unsigned u = __builtin_bit_cast(unsigned, f);
    return (short)(unsigned short)((u + 0x8000u) >> 16);
}
static __device__ __forceinline__ short f2bf_rne(float f) {  // weights
    unsigned u = __builtin_bit_cast(unsigned, f);
    unsigned r = (u + 0x7FFFu + ((u >> 16) & 1u)) >> 16;
    return (short)(unsigned short)r;
}
static __device__ __forceinline__ float bf2f(short s) {
    unsigned u = ((unsigned)(unsigned short)s) << 16;
    return __builtin_bit_cast(float, u);
}
static __device__ __forceinline__ float4_t mfma16(short8 a, short8 b, float4_t c) {
    return __builtin_amdgcn_mfma_f32_16x16x32_bf16(
        __builtin_bit_cast(bf16x8_t, a), __builtin_bit_cast(bf16x8_t, b), c, 0, 0, 0);
}
static __device__ __forceinline__ float sigm(float x) {
    return __builtin_amdgcn_rcpf(1.0f + __expf(-x));
}
static __device__ __forceinline__ float tanh_f(float x) {
    return 1.0f - 2.0f * __builtin_amdgcn_rcpf(1.0f + __expf(2.0f * x));
}

// ---- workspace layout (bytes) ----
#define WS_WU1 0
#define WS_WU2 49152
#define WS_WD  98304
#define WS_BZ1 102400
#define WS_B2P 103424
#define WS_BDP 104448
#define WS_DG  104576

// Pre-swizzle weights into MFMA B-fragment order: frag f, lane l, elem e ->
// B[k = kt*32 + (l>>4)*8 + e][n]. Stored as [f][lane][8] so frag read = 1 ds_read_b128.
__global__ void precompute(const float* __restrict__ W1, const float* __restrict__ U1,
                           const float* __restrict__ b1, const float* __restrict__ Wd,
                           const float* __restrict__ bd, const float* __restrict__ W2,
                           const float* __restrict__ U2, const float* __restrict__ b2,
                           short* __restrict__ wu1_sw, short* __restrict__ wu2_sw,
                           short* __restrict__ wd_sw, float* __restrict__ bz1,
                           float* __restrict__ b2p, float* __restrict__ bdp) {
    const int lane = threadIdx.x;  // 64
    const int b = blockIdx.x;      // 101
    if (b < 48) {
        const int f = b, jt = f / 12, g = (f / 3) & 3, kt = f % 3;
        const int col = g * 64 + jt * 16 + (lane & 15);
        for (int e = 0; e < 8; ++e) {
            const int k = kt * 32 + (lane >> 4) * 8 + e;
            float v = 0.0f;
            if (k < 64)      v = U1[k * G4H + col];          // h1 rows
            else if (k < 80) v = W1[(k - 64) * G4H + col];   // x rows
            wu1_sw[(f * 64 + lane) * 8 + e] = f2bf_rne(v);
        }
    } else if (b < 96) {
        const int f = b - 48, jt = f / 12, g = (f / 3) & 3, kt = f % 3;
        const int col = g * 64 + jt * 16 + (lane & 15);
        for (int e = 0; e < 8; ++e) {
            const int k = kt * 32 + (lane >> 4) * 8 + e;
            float v = 0.0f;
            if (k < 32)      v = (k < D_MLP) ? W2[k * G4H + col] : 0.0f;  // d rows
            else             v = U2[(k - 32) * G4H + col];                 // h2 rows
            wu2_sw[(f * 64 + lane) * 8 + e] = f2bf_rne(v);
        }
    } else if (b < 100) {
        const int fd = b - 96, nt = fd >> 1, kt = fd & 1;
        const int col = nt * 16 + (lane & 15);
        for (int e = 0; e < 8; ++e) {
            const int k = kt * 32 + (lane >> 4) * 8 + e;  // h1 row 0..63
            const float v = (col < D_MLP) ? Wd[k * D_MLP + col] : 0.0f;
            wd_sw[(fd * 64 + lane) * 8 + e] = f2bf_rne(v);
        }
    } else {
        for (int i = 0; i < 4; ++i) {
            const int c = i * 64 + lane;
            bz1[c] = b1[c];
            b2p[c] = b2[c];
        }
        if (lane < 32) bdp[lane] = (lane < D_MLP) ? bd[lane] : 0.0f;
    }
}

// ---------------- lstm1: autonomous waves, d = h1@Wd+bd out to global (coalesced) ----------------
__global__ __launch_bounds__(256)
__attribute__((amdgpu_waves_per_eu(3, 4)))
void lstm1(const float* __restrict__ x, const short* __restrict__ wu1_sw,
           const short* __restrict__ wd_sw, const float* __restrict__ bz1,
           const float* __restrict__ bdp, short* __restrict__ dg) {
    __shared__ __align__(16) short W[40 * 512];        // frags 0..35 gate (jt 0..2) + 4 wd
    __shared__ __align__(16) short plane[4][16 * PSTR];
    __shared__ __align__(16) short dstg[4][16 * DSTR]; // per-wave d staging (coalesce bounce)

    const int tid = threadIdx.x, lane = tid & 63, wave = tid >> 6;
    const int q = lane >> 4, n = lane & 15;
    const int rowbase = blockIdx.x * 64 + wave * 16;

    // stage LDS weights (one barrier, then none)
    for (int i = tid; i < 40 * 64; i += 256) {
        const short8 v = (i < 36 * 64) ? ((const short8*)wu1_sw)[i]
                                       : ((const short8*)wd_sw)[i - 36 * 64];
        ((short8*)W)[i] = v;
    }
    // jt=3 gate frags live in registers
    short8 wf[4][3];
#pragma unroll
    for (int g = 0; g < 4; ++g)
#pragma unroll
        for (int kt = 0; kt < 3; ++kt)
            wf[g][kt] = ((const short8*)wu1_sw)[(36 + g * 3 + kt) * 64 + lane];
    float bz[4][4];
#pragma unroll
    for (int jt = 0; jt < 4; ++jt)
#pragma unroll
        for (int g = 0; g < 4; ++g) bz[jt][g] = bz1[g * 64 + jt * 16 + n];
    const float bdv0 = bdp[n], bdv1 = bdp[16 + n];

    short* pl = &plane[wave][0];
    short* dbw = &dstg[wave][0];
    for (int i = lane; i < 16 * PSTR; i += 64) pl[i] = 0;

    float4_t c1[4];
#pragma unroll
    for (int jt = 0; jt < 4; ++jt) c1[jt] = (float4_t){0, 0, 0, 0};

    __syncthreads();  // weights visible; no further barriers

    const float* xlane = x + (size_t)(rowbase + n) * (T_STEPS * D_IN) + (q & 1) * 8;
    const int drr = lane >> 2, dch = lane & 3;  // d flush: row, 16B-chunk

    for (int t = 0; t < T_STEPS; ++t) {
        // A-frags: h1_{t-1} from private plane (k-tiles 0,1)
        const short8 ah0 = *(const short8*)&pl[n * PSTR + q * 8];
        const short8 ah1 = *(const short8*)&pl[n * PSTR + 32 + q * 8];

        // pipelined d_{t-1} = h1_{t-1} @ Wd + bd  (uses same A-frags)
        if (t > 0) {
            const short8* WD = (const short8*)&W[36 * 512];
            float4_t d0 = (float4_t){bdv0, bdv0, bdv0, bdv0};
            float4_t d1 = (float4_t){bdv1, bdv1, bdv1, bdv1};
            d0 = mfma16(ah0, WD[0 * 64 + lane], d0);
            d0 = mfma16(ah1, WD[1 * 64 + lane], d0);
            d1 = mfma16(ah0, WD[2 * 64 + lane], d1);
            d1 = mfma16(ah1, WD[3 * 64 + lane], d1);
            // C-layout -> wave-private LDS tile
#pragma unroll
            for (int jj = 0; jj < 4; ++jj) {
                dbw[(q * 4 + jj) * DSTR + n] = f2bf(d0[jj]);
                dbw[(q * 4 + jj) * DSTR + 16 + n] = f2bf(d1[jj]);
            }
            __builtin_amdgcn_wave_barrier();  // keep write->read order (same wave, in-order LDS pipe)
            const short8 dv = *(const short8*)&dbw[drr * DSTR + dch * 8];
            *(short8*)(dg + ((size_t)(t - 1) * B_TOT + rowbase + drr) * 32 + dch * 8) = dv;
            __builtin_amdgcn_wave_barrier();  // WAR: dbw reused next t
        }

        // x_t A-frag (k-tile 2): lanes q<2 hold x cols, q>=2 hold zero-weight rows
        short8 a2 = (short8){0, 0, 0, 0, 0, 0, 0, 0};
        if (q < 2) {
            const float* xp = xlane + t * D_IN;
            const float4 x0 = *(const float4*)xp;
            const float4 x1 = *(const float4*)(xp + 4);
            a2[0] = f2bf(x0.x); a2[1] = f2bf(x0.y); a2[2] = f2bf(x0.z); a2[3] = f2bf(x0.w);
            a2[4] = f2bf(x1.x); a2[5] = f2bf(x1.y); a2[6] = f2bf(x1.z); a2[7] = f2bf(x1.w);
        }

#pragma unroll
        for (int jt = 0; jt < 4; ++jt) {
            float4_t ac[4];
#pragma unroll
            for (int g = 0; g < 4; ++g) {
                short8 b0, b1, b2v;
                if (jt < 3) {
                    const int fb = (jt * 4 + g) * 3;
                    b0 = ((const short8*)W)[(fb + 0) * 64 + lane];
                    b1 = ((const short8*)W)[(fb + 1) * 64 + lane];
                    b2v = ((const short8*)W)[(fb + 2) * 64 + lane];
                } else { b0 = wf[g][0]; b1 = wf[g][1]; b2v = wf[g][2]; }
                float4_t c = (float4_t){bz[jt][g], bz[jt][g], bz[jt][g], bz[jt][g]};
                c = mfma16(ah0, b0, c);
                c = mfma16(ah1, b1, c);
                c = mfma16(a2, b2v, c);
                ac[g] = c;
            }
#pragma unroll
            for (int jj = 0; jj < 4; ++jj) {
                const float iv = sigm(ac[0][jj]);
                const float fv = sigm(ac[1][jj]);
                const float gv = tanh_f(ac[2][jj]);
                const float ov = sigm(ac[3][jj]);
                const float cn = fv * c1[jt][jj] + iv * gv;
                c1[jt][jj] = cn;
                pl[(q * 4 + jj) * PSTR + jt * 16 + n] = f2bf(ov * tanh_f(cn));
            }
        }
    }
    // final d_9
    {
        const short8 ah0 = *(const short8*)&pl[n * PSTR + q * 8];
        const short8 ah1 = *(const short8*)&pl[n * PSTR + 32 + q * 8];
        const short8* WD = (const short8*)&W[36 * 512];
        float4_t d0 = (float4_t){bdv0, bdv0, bdv0, bdv0};
        float4_t d1 = (float4_t){bdv1, bdv1, bdv1, bdv1};
        d0 = mfma16(ah0, WD[0 * 64 + lane], d0);
        d0 = mfma16(ah1, WD[1 * 64 + lane], d0);
        d1 = mfma16(ah0, WD[2 * 64 + lane], d1);
        d1 = mfma16(ah1, WD[3 * 64 + lane], d1);
#pragma unroll
        for (int jj = 0; jj < 4; ++jj) {
            dbw[(q * 4 + jj) * DSTR + n] = f2bf(d0[jj]);
            dbw[(q * 4 + jj) * DSTR + 16 + n] = f2bf(d1[jj]);
        }
        __builtin_amdgcn_wave_barrier();
        const short8 dv = *(const short8*)&dbw[drr * DSTR + dch * 8];
        *(short8*)(dg + ((size_t)(T_STEPS - 1) * B_TOT + rowbase + drr) * 32 + dch * 8) = dv;
    }
}

// ---------------- lstm2: autonomous waves, d from global as A-frags, fused projection ----------------
__global__ __launch_bounds__(256)
__attribute__((amdgpu_waves_per_eu(3, 4)))
void lstm2(const short* __restrict__ dg, const short* __restrict__ wu2_sw,
           const float* __restrict__ b2p, const float* __restrict__ Wf,
           const float* __restrict__ bfin, float* __restrict__ out) {
    __shared__ __align__(16) short W[36 * 512];
    __shared__ __align__(16) short plane[4][16 * PSTR];

    const int tid = threadIdx.x, lane = tid & 63, wave = tid >> 6;
    const int q = lane >> 4, n = lane & 15;
    const int rowbase = blockIdx.x * 64 + wave * 16;

    for (int i = tid; i < 36 * 64; i += 256)
        ((short8*)W)[i] = ((const short8*)wu2_sw)[i];
    short8 wf[4][3];
#pragma unroll
    for (int g = 0; g < 4; ++g)
#pragma unroll
        for (int kt = 0; kt < 3; ++kt)
            wf[g][kt] = ((const short8*)wu2_sw)[(36 + g * 3 + kt) * 64 + lane];
    float bz[4][4];
#pragma unroll
    for (int jt = 0; jt < 4; ++jt)
#pragma unroll
        for (int g = 0; g < 4; ++g) bz[jt][g] = b2p[g * 64 + jt * 16 + n];

    short* pl = &plane[wave][0];
    for (int i = lane; i < 16 * PSTR; i += 64) pl[i] = 0;

    float4_t c2[4];
#pragma unroll
    for (int jt = 0; jt < 4; ++jt) c2[jt] = (float4_t){0, 0, 0, 0};

    __syncthreads();  // weights visible; no further barriers

    const short8* dfr = (const short8*)dg + (size_t)(rowbase + n) * 4 + q;

    for (int t = 0; t < T_STEPS; ++t) {
        const short8 ad = dfr[(size_t)t * (B_TOT * 4)];          // d_t (k-tile 0)
        const short8 ah0 = *(const short8*)&pl[n * PSTR + q * 8];       // h2 k-tile 1
        const short8 ah1 = *(const short8*)&pl[n * PSTR + 32 + q * 8];  // h2 k-tile 2

#pragma unroll
        for (int jt = 0; jt < 4; ++jt) {
            float4_t ac[4];
#pragma unroll
            for (int g = 0; g < 4; ++g) {
                short8 b0, b1, b2v;
                if (jt < 3) {
                    const int fb = (jt * 4 + g) * 3;
                    b0 = ((const short8*)W)[(fb + 0) * 64 + lane];
                    b1 = ((const short8*)W)[(fb + 1) * 64 + lane];
                    b2v = ((const short8*)W)[(fb + 2) * 64 + lane];
                } else { b0 = wf[g][0]; b1 = wf[g][1]; b2v = wf[g][2]; }
                float4_t c = (float4_t){bz[jt][g], bz[jt][g], bz[jt][g], bz[jt][g]};
                c = mfma16(ad, b0, c);
                c = mfma16(ah0, b1, c);
                c = mfma16(ah1, b2v, c);
                ac[g] = c;
            }
#pragma unroll
            for (int jj = 0; jj < 4; ++jj) {
                const float iv = sigm(ac[0][jj]);
                const float fv = sigm(ac[1][jj]);
                const float gv = fmaxf(ac[2][jj], 0.0f);
                const float ov = sigm(ac[3][jj]);
                const float cn = fv * c2[jt][jj] + iv * gv;
                c2[jt][jj] = cn;
                pl[(q * 4 + jj) * PSTR + jt * 16 + n] = f2bf(ov * fmaxf(cn, 0.0f));
            }
        }
    }

    // out = h2_9 @ Wf + bf  (per-wave, from private plane)
    {
        const int r = lane >> 2, cc = lane & 3;
        float s = bfin[cc];
#pragma unroll
        for (int kb = 0; kb < 8; ++kb) {
            const short8 h8 = *(const short8*)&pl[r * PSTR + kb * 8];
#pragma unroll
            for (int e = 0; e < 8; ++e)
                s += bf2f(h8[e]) * Wf[(kb * 8 + e) * D_OUT + cc];
        }
        out[(size_t)(rowbase + r) * D_OUT + cc] = s;
    }
}

extern "C" void kernel_launch(void* const* d_in, const int* in_sizes, int n_in,
                              void* d_out, int out_size, void* d_ws, size_t ws_size,
                              hipStream_t stream) {
    const float* x  = (const float*)d_in[0];
    const float* W1 = (const float*)d_in[1];
    const float* U1 = (const float*)d_in[2];
    const float* b1 = (const float*)d_in[3];
    const float* Wd = (const float*)d_in[4];
    const float* bd = (const float*)d_in[5];
    const float* W2 = (const float*)d_in[6];
    const float* U2 = (const float*)d_in[7];
    const float* b2 = (const float*)d_in[8];
    const float* Wf = (const float*)d_in[9];
    const float* bf = (const float*)d_in[10];
    float* out = (float*)d_out;

    char* ws = (char*)d_ws;
    short* wu1_sw = (short*)(ws + WS_WU1);
    short* wu2_sw = (short*)(ws + WS_WU2);
    short* wd_sw  = (short*)(ws + WS_WD);
    float* bz1    = (float*)(ws + WS_BZ1);
    float* b2p    = (float*)(ws + WS_B2P);
    float* bdp    = (float*)(ws + WS_BDP);
    short* dg     = (short*)(ws + WS_DG);

    precompute<<<101, 64, 0, stream>>>(W1, U1, b1, Wd, bd, W2, U2, b2,
                                       wu1_sw, wu2_sw, wd_sw, bz1, b2p, bdp);
    lstm1<<<B_TOT / 64, 256, 0, stream>>>(x, wu1_sw, wd_sw, bz1, bdp, dg);
    lstm2<<<B_TOT / 64, 256, 0, stream>>>(dg, wu2_sw, b2p, Wf, bf, out);
}

// Round 7
// 195.193 us; speedup vs baseline: 4.2983x; 2.7656x over previous
//
#include <hip/hip_runtime.h>

#define B_TOT 65536
#define T_STEPS 10
#define D_IN 16
#define H 64
#define G4H 256
#define D_MLP 30
#define D_OUT 4
#define BTILE 32
#define PSTR 88     // plane row stride (shorts): [x(0:16)|h1(16:80)] p1 / [h2(0:64)] p2
#define DSTR 34     // d buffer row stride (shorts): 32 cols + pad (17 dw, odd -> ~2-way)

typedef short short8 __attribute__((ext_vector_type(8)));
typedef short short4_t __attribute__((ext_vector_type(4)));
typedef float float4_t __attribute__((ext_vector_type(4)));
typedef __bf16 bf16x8_t __attribute__((ext_vector_type(8)));

static __device__ __forceinline__ short f2bf(float f) {  // round-half-up (activations)
    unsigned u = __builtin_bit_cast(unsigned, f);
    return (short)(unsigned short)((u + 0x8000u) >> 16);
}
static __device__ __forceinline__ short f2bf_rne(float f) {  // weights
    unsigned u = __builtin_bit_cast(unsigned, f);
    unsigned r = (u + 0x7FFFu + ((u >> 16) & 1u)) >> 16;
    return (short)(unsigned short)r;
}
static __device__ __forceinline__ float bf2f(short s) {
    unsigned u = ((unsigned)(unsigned short)s) << 16;
    return __builtin_bit_cast(float, u);
}
static __device__ __forceinline__ float4_t mfma16(short8 a, short8 b, float4_t c) {
    return __builtin_amdgcn_mfma_f32_16x16x32_bf16(
        __builtin_bit_cast(bf16x8_t, a), __builtin_bit_cast(bf16x8_t, b), c, 0, 0, 0);
}
static __device__ __forceinline__ float sigm(float x) {
    return __builtin_amdgcn_rcpf(1.0f + __expf(-x));
}
static __device__ __forceinline__ float tanh_f(float x) {
    return 1.0f - 2.0f * __builtin_amdgcn_rcpf(1.0f + __expf(2.0f * x));
}

// ---- workspace layout (bytes) ----
#define WS_WU1 0        // 48 frags x 1KB = 49152
#define WS_WU2 49152    // 48 frags = 49152
#define WS_WD  98304    // 4 frags = 4096
#define WS_BZ1 102400   // 256 f32
#define WS_B2P 103424   // 256 f32
#define WS_BDP 104448   // 32 f32

// Weights pre-swizzled into MFMA B-frag order: frag f, lane l, elem e ->
// B[k = (l>>4)*8+e][n = l&15]; one frag read = 1 ds/global b128.
// wu1: A1=[x(0:16)|h1(16:80)], k-tiles at A-cols 0/32/48 (overlap trick):
//   kt0: [W1(16); U1[0:16]]   kt1: U1[16:48]   kt2: [zeros(16); U1[48:64]]
// wu2: A2=[d(0:32)|h2(0:64 of plane)], kt0: [W2(30);0;0], kt1: U2[0:32], kt2: U2[32:64]
// wd : d = h1 @ Wd (cols padded 30->32), frags fd = nt*2+kt
__global__ void precompute(const float* __restrict__ W1, const float* __restrict__ U1,
                           const float* __restrict__ b1, const float* __restrict__ Wd,
                           const float* __restrict__ bd, const float* __restrict__ W2,
                           const float* __restrict__ U2, const float* __restrict__ b2,
                           short* __restrict__ wu1_sw, short* __restrict__ wu2_sw,
                           short* __restrict__ wd_sw, float* __restrict__ bz1,
                           float* __restrict__ b2p, float* __restrict__ bdp) {
    const int lane = threadIdx.x;  // 64
    const int b = blockIdx.x;      // 101
    if (b < 48) {
        const int f = b, jt = f / 12, g = (f / 3) & 3, kt = f % 3;
        const int col = g * 64 + jt * 16 + (lane & 15);
        for (int e = 0; e < 8; ++e) {
            const int sub = (lane >> 4) * 8 + e;  // 0..31
            float v;
            if (kt == 0)      v = (sub < 16) ? W1[sub * G4H + col] : U1[(sub - 16) * G4H + col];
            else if (kt == 1) v = U1[(sub + 16) * G4H + col];
            else              v = (sub < 16) ? 0.0f : U1[(sub + 32) * G4H + col];
            wu1_sw[(f * 64 + lane) * 8 + e] = f2bf_rne(v);
        }
    } else if (b < 96) {
        const int f = b - 48, jt = f / 12, g = (f / 3) & 3, kt = f % 3;
        const int col = g * 64 + jt * 16 + (lane & 15);
        for (int e = 0; e < 8; ++e) {
            const int k = kt * 32 + (lane >> 4) * 8 + e;
            float v;
            if (k < 32) v = (k < D_MLP) ? W2[k * G4H + col] : 0.0f;  // d rows
            else        v = U2[(k - 32) * G4H + col];                // h2 rows
            wu2_sw[(f * 64 + lane) * 8 + e] = f2bf_rne(v);
        }
    } else if (b < 100) {
        const int fd = b - 96, nt = fd >> 1, kt = fd & 1;
        const int col = nt * 16 + (lane & 15);
        for (int e = 0; e < 8; ++e) {
            const int k = kt * 32 + (lane >> 4) * 8 + e;  // h1 dim 0..63
            const float v = (col < D_MLP) ? Wd[k * D_MLP + col] : 0.0f;
            wd_sw[(fd * 64 + lane) * 8 + e] = f2bf_rne(v);
        }
    } else {
        for (int i = 0; i < 4; ++i) {
            const int c = i * 64 + lane;
            bz1[c] = b1[c];
            b2p[c] = b2[c];
        }
        if (lane < 32) bdp[lane] = (lane < D_MLP) ? bd[lane] : 0.0f;
    }
}

// ---------------- fully fused: LSTM1 -> Dense(d in LDS) -> LSTM2 -> projection ----------------
__global__ __launch_bounds__(256)
__attribute__((amdgpu_waves_per_eu(3, 4)))
void lstm_all(const float* __restrict__ x, const short* __restrict__ wu1_sw,
              const short* __restrict__ wu2_sw, const short* __restrict__ wd_sw,
              const float* __restrict__ bz1, const float* __restrict__ b2p,
              const float* __restrict__ bdp, const float* __restrict__ Wf,
              const float* __restrict__ bfin, float* __restrict__ out) {
    __shared__ __align__(16) short P[2][BTILE * PSTR];          // 11 KB activation plane
    __shared__ __align__(16) short D[T_STEPS][BTILE * DSTR];    // 21.25 KB dense buffer

    const int tid = threadIdx.x, lane = tid & 63, wave = tid >> 6;
    const int q = lane >> 4, n = lane & 15;
    const int b0 = blockIdx.x * BTILE;

    // ---- phase-1 weights: wave owns gate-col slice [g*64 + wave*16, +16) ----
    short8 wz[4][3];
    float bzv[4];
#pragma unroll
    for (int g = 0; g < 4; ++g) {
#pragma unroll
        for (int kt = 0; kt < 3; ++kt)
            wz[g][kt] = ((const short8*)wu1_sw)[(wave * 12 + g * 3 + kt) * 64 + lane];
        bzv[g] = bz1[g * 64 + wave * 16 + n];
    }
    // d-projection: wave -> (row-tile mw = wave>>1, col-tile nt = wave&1)
    const int mw = wave >> 1, ntw = wave & 1;
    const short8 wd0 = ((const short8*)wd_sw)[(ntw * 2 + 0) * 64 + lane];
    const short8 wd1 = ((const short8*)wd_sw)[(ntw * 2 + 1) * 64 + lane];
    const float bdv = bdp[ntw * 16 + n];

    for (int i = tid; i < BTILE * PSTR; i += 256) P[0][i] = 0;

    float4_t cc[2];
    cc[0] = (float4_t){0, 0, 0, 0};
    cc[1] = (float4_t){0, 0, 0, 0};

    const int xr = tid >> 2, xs = tid & 3;  // tid<128: rows 0..31, 4-float segs
    const float* xbase = x + (size_t)(b0 + (xr & 31)) * (T_STEPS * D_IN) + xs * 4;
    float4 xv;
    if (tid < 128) xv = *(const float4*)xbase;
    __syncthreads();  // zeros done
    if (tid < 128) {
        short4_t s4;
        s4[0] = f2bf(xv.x); s4[1] = f2bf(xv.y); s4[2] = f2bf(xv.z); s4[3] = f2bf(xv.w);
        *(short4_t*)&P[0][xr * PSTR + xs * 4] = s4;
    }
    __syncthreads();  // x_0 staged

    // ================= phase 1: LSTM1 (tanh) + Dense into D =================
    for (int t = 0; t < T_STEPS; ++t) {
        const short* cb = P[t & 1];
        short* nb = P[(t & 1) ^ 1];
        if (tid < 128) {
            const int tn = (t + 1 < T_STEPS) ? t + 1 : T_STEPS - 1;
            xv = *(const float4*)(xbase + tn * D_IN);
        }

#pragma unroll
        for (int m = 0; m < 2; ++m) {
            const int arow = (16 * m + n) * PSTR + q * 8;
            const short8 a0 = *(const short8*)&cb[arow + 0];
            const short8 a1 = *(const short8*)&cb[arow + 32];
            const short8 a2 = *(const short8*)&cb[arow + 48];  // overlap k-tile
            float4_t ac[4];
#pragma unroll
            for (int g = 0; g < 4; ++g) {
                float4_t c = (float4_t){bzv[g], bzv[g], bzv[g], bzv[g]};
                c = mfma16(a0, wz[g][0], c);
                c = mfma16(a1, wz[g][1], c);
                c = mfma16(a2, wz[g][2], c);
                ac[g] = c;
            }
#pragma unroll
            for (int jj = 0; jj < 4; ++jj) {
                const float iv = sigm(ac[0][jj]);
                const float fv = sigm(ac[1][jj]);
                const float gv = tanh_f(ac[2][jj]);
                const float ov = sigm(ac[3][jj]);
                const float cn = fv * cc[m][jj] + iv * gv;
                cc[m][jj] = cn;
                nb[(16 * m + q * 4 + jj) * PSTR + 16 + wave * 16 + n] = f2bf(ov * tanh_f(cn));
            }
        }
        if (tid < 128) {
            short4_t s4;
            s4[0] = f2bf(xv.x); s4[1] = f2bf(xv.y); s4[2] = f2bf(xv.z); s4[3] = f2bf(xv.w);
            *(short4_t*)&nb[xr * PSTR + xs * 4] = s4;
        }
        __syncthreads();  // h1_t + x_{t+1} visible

        // d_t = h1_t @ Wd + bd  -> D[t]  (each wave: one 16x16 tile, k=64)
        {
            const int drow = (16 * mw + n) * PSTR + q * 8;
            const short8 dh0 = *(const short8*)&nb[drow + 16];
            const short8 dh1 = *(const short8*)&nb[drow + 48];
            float4_t dd = (float4_t){bdv, bdv, bdv, bdv};
            dd = mfma16(dh0, wd0, dd);
            dd = mfma16(dh1, wd1, dd);
            short* dt = &D[t][0];
#pragma unroll
            for (int jj = 0; jj < 4; ++jj)
                dt[(16 * mw + q * 4 + jj) * DSTR + ntw * 16 + n] = f2bf(dd[jj]);
        }
    }

    // ================= phase boundary: swap weights, reset state =================
    __syncthreads();  // last D writes + plane reads done
#pragma unroll
    for (int g = 0; g < 4; ++g) {
#pragma unroll
        for (int kt = 0; kt < 3; ++kt)
            wz[g][kt] = ((const short8*)wu2_sw)[(wave * 12 + g * 3 + kt) * 64 + lane];
        bzv[g] = b2p[g * 64 + wave * 16 + n];
    }
    cc[0] = (float4_t){0, 0, 0, 0};
    cc[1] = (float4_t){0, 0, 0, 0};
    // zero h2 region of P[0] (rows 0..31, cols 0..63)
    {
        const int zr = tid >> 3, zc = (tid & 7) * 8;
        *(short8*)&P[0][zr * PSTR + zc] = (short8){0, 0, 0, 0, 0, 0, 0, 0};
    }
    __syncthreads();

    // ================= phase 2: LSTM2 (relu) from D =================
    for (int t = 0; t < T_STEPS; ++t) {
        const short* cb = P[t & 1];
        short* nb = P[(t & 1) ^ 1];

#pragma unroll
        for (int m = 0; m < 2; ++m) {
            const int ar = 16 * m + n;
            const short8 ad  = *(const short8*)&D[t][ar * DSTR + q * 8];
            const short8 ah0 = *(const short8*)&cb[ar * PSTR + q * 8];
            const short8 ah1 = *(const short8*)&cb[ar * PSTR + 32 + q * 8];
            float4_t ac[4];
#pragma unroll
            for (int g = 0; g < 4; ++g) {
                float4_t c = (float4_t){bzv[g], bzv[g], bzv[g], bzv[g]};
                c = mfma16(ad, wz[g][0], c);
                c = mfma16(ah0, wz[g][1], c);
                c = mfma16(ah1, wz[g][2], c);
                ac[g] = c;
            }
#pragma unroll
            for (int jj = 0; jj < 4; ++jj) {
                const float iv = sigm(ac[0][jj]);
                const float fv = sigm(ac[1][jj]);
                const float gv = fmaxf(ac[2][jj], 0.0f);
                const float ov = sigm(ac[3][jj]);
                const float cn = fv * cc[m][jj] + iv * gv;
                cc[m][jj] = cn;
                nb[(16 * m + q * 4 + jj) * PSTR + wave * 16 + n] = f2bf(ov * fmaxf(cn, 0.0f));
            }
        }
        __syncthreads();
    }

    // ---- out = h2_9 @ Wf + bf ; t=9 wrote nb = P[0] ----
    if (tid < 128) {
        const int r = tid >> 2, c = tid & 3;
        float s = bfin[c];
#pragma unroll
        for (int kb = 0; kb < 8; ++kb) {
            const short8 h8 = *(const short8*)&P[0][r * PSTR + kb * 8];
#pragma unroll
            for (int e = 0; e < 8; ++e)
                s += bf2f(h8[e]) * Wf[(kb * 8 + e) * D_OUT + c];
        }
        out[(size_t)(b0 + r) * D_OUT + c] = s;
    }
}

extern "C" void kernel_launch(void* const* d_in, const int* in_sizes, int n_in,
                              void* d_out, int out_size, void* d_ws, size_t ws_size,
                              hipStream_t stream) {
    const float* x  = (const float*)d_in[0];
    const float* W1 = (const float*)d_in[1];
    const float* U1 = (const float*)d_in[2];
    const float* b1 = (const float*)d_in[3];
    const float* Wd = (const float*)d_in[4];
    const float* bd = (const float*)d_in[5];
    const float* W2 = (const float*)d_in[6];
    const float* U2 = (const float*)d_in[7];
    const float* b2 = (const float*)d_in[8];
    const float* Wf = (const float*)d_in[9];
    const float* bf = (const float*)d_in[10];
    float* out = (float*)d_out;

    char* ws = (char*)d_ws;
    short* wu1_sw = (short*)(ws + WS_WU1);
    short* wu2_sw = (short*)(ws + WS_WU2);
    short* wd_sw  = (short*)(ws + WS_WD);
    float* bz1    = (float*)(ws + WS_BZ1);
    float* b2p    = (float*)(ws + WS_B2P);
    float* bdp    = (float*)(ws + WS_BDP);

    precompute<<<101, 64, 0, stream>>>(W1, U1, b1, Wd, bd, W2, U2, b2,
                                       wu1_sw, wu2_sw, wd_sw, bz1, b2p, bdp);
    lstm_all<<<B_TOT / BTILE, 256, 0, stream>>>(x, wu1_sw, wu2_sw, wd_sw,
                                                bz1, b2p, bdp, Wf, bf, out);
}